// Round 1
// 685.285 us; speedup vs baseline: 1.0245x; 1.0245x over previous
//
#include <hip/hip_runtime.h>
#include <cmath>

// All implicit ops single-rounded; FMA only where written explicitly
// (replicating XLA:CPU's FPOpFusion::Fast contraction). Output must stay
// BIT-IDENTICAL to prior rounds (passed, absmax 16.0).
#pragma clang fp contract(off)

#define PI_F     3.141592653589793f
#define TWOPI_F  6.283185307179586f
#define EPS_F    1e-5f
#define TWOEPS_F 2e-5f   // == f32(2e-5) exactly

// Packed 2xf32 — maps to v_pk_{add,mul,fma}_f32 on gfx950. Per-lane IEEE
// semantics identical to the scalar ops, so results are bit-identical;
// packing only halves the VALU issue count on paired computations.
typedef float v2f __attribute__((ext_vector_type(2)));

__device__ __forceinline__ v2f pk_fma(v2f a, v2f b, v2f c) {
    return __builtin_elementwise_fma(a, b, c);
}

// ---------------------------------------------------------------------------
// Branchless fused replica of glibc (>=2.28) scalar sinf/cosf (see prior
// session notes for the bit-exactness argument). Parity/sign selects applied
// AFTER the f64->f32 rounding — IEEE rounding commutes with sign flip.
// Valid for |y| < 120 (reduce_fast range); rollout angles stay |q| < ~30.
// ---------------------------------------------------------------------------
__device__ __forceinline__ void gl_sincos(float y, float& sout, float& cout) {
    const double hpi_inv = 0x1.45F306DC9C883p+23;  // 2/pi * 2^24
    const double hpi     = 0x1.921FB54442D18p+0;   // pi/2
    const double ps1 = -0x1.555545995a603p-3;
    const double ps2 =  0x1.1107605230bc4p-7;
    const double ps3 = -0x1.994eb3774cf24p-13;
    const double pc1 = -0x1.ffffffd0c621cp-2;
    const double pc2 =  0x1.55553e1068f19p-5;
    const double pc3 = -0x1.6c087e89a359dp-10;
    const double pc4 =  0x1.99343027bf8c3p-16;

    double x = (double)y;
    double r = x * hpi_inv;
    int n = ((int)r + 0x800000) >> 24;     // trunc + biased round, glibc exact
    double xr = x - (double)n * hpi;       // separate mul + sub (no fma)
    double x2 = xr * xr;

    // sine poly at xr, glibc grouping
    double x3 = xr * x2;
    double s1 = ps2 + x2 * ps3;
    double x7 = x3 * x2;
    double ss = xr + x3 * ps1;
    double psin = ss + x7 * s1;

    // cosine poly at x2, positive table, glibc grouping
    double x4 = x2 * x2;
    double c2 = pc3 + x2 * pc4;
    double c1 = 1.0 + x2 * pc1;
    double x6 = x4 * x2;
    double cc = c1 + x4 * pc2;
    double pcos = cc + x6 * c2;

    // round once, then exact sign/parity selects in f32
    float psin_f = (float)psin;
    float pcos_f = (float)pcos;
    float s_sel = (n & 1) ? pcos_f : psin_f;
    float c_sel = (n & 1) ? psin_f : pcos_f;
    sout = (n & 2) ? -s_sel : s_sel;
    cout = ((n + 1) & 2) ? -c_sel : c_sel;
}

__device__ __forceinline__ float gl_cosf(float y) {
    float s, c;
    gl_sincos(y, s, c);
    return c;
}

// ---------------------------------------------------------------------------
// angnorm with an exact bounded-range fmod, replacing the OCML fmodf libcall.
// fmod(t, c) is the EXACT remainder (uniquely defined real number, rounded
// never — it is always representable), so ANY correct implementation is
// bit-identical to fmodf. Correctness for |t| < 64, c = f32(2pi):
//   * k = trunc(t/c): computed as trunc(f64(t) * RN64(1/c)). Relative error
//     <= 2^-52. If t is NOT an exact multiple of c, the exact quotient is at
//     least 2^-21/c ~ 2^-23.6 away from any integer (t - m*c is a nonzero
//     dyadic with lowest bit >= 2^-21 since |t| >= c => ulp(t) >= 2^-21),
//     so trunc is exact. If t IS an exact multiple, k may be off by one.
//   * r = fmaf(-k, c, t) = t - k*c rounded once. With correct k, the true
//     remainder spans at most weights 2^2 .. 2^-21 = 24 bits => representable
//     => r is EXACT. With k off by one (exact-multiple case) r = +/-c exactly.
//   * Interval fixups (r -= c / r += c) only trigger in the exact-multiple
//     case and are exact (c - c = +0). fmodf would return -0 for negative
//     exact multiples where we produce +0; both give identical bits after
//     the subsequent (r - pi), so the discrepancy is unobservable.
// ---------------------------------------------------------------------------
__device__ __forceinline__ float angnorm(float x) {
    const double inv_twopi = 1.0 / (double)TWOPI_F;  // RN64(1/f32(2pi))
    float t = x + PI_F;
    int k = (int)((double)t * inv_twopi);            // trunc toward zero
    float r = __builtin_fmaf((float)(-k), TWOPI_F, t);
    if (r >= TWOPI_F)  r -= TWOPI_F;   // k one too small at exact multiple
    if (r <= -TWOPI_F) r += TWOPI_F;   // k one too large at exact multiple
    if (r < 0.0f) r += TWOPI_F;        // reference's sign fixup (jnp.mod)
    return r - PI_F;
}

// ---------------------------------------------------------------------------
// Cross-step trig cache, extended with the q-only-derived Hamiltonian terms
// (denominators and potential energies). These were recomputed by grads_full
// across the loop back-edge every step (GVN does not eliminate loop-carried
// redundancy through the phi); hoisting them here removes ~21 ops/step and
// lets the +/-eps pairs live pre-packed in v2f registers.
// Pair convention: .x = +eps variant, .y = -eps variant.
// ---------------------------------------------------------------------------
struct QTrig {
    float cdq, den0, vv0;        // base: cos(dq), 2*fma(s,s,1), (1-c1)+(1-c2)
    v2f c_q1, den_q1, vv_q1;     // q1+/-eps: cos((q1+/-e)-q2), denom, VV
    v2f c_q2, den_q2, vv_q2;     // q2+/-eps: cos(q1-(q2+/-e)), denom, VV
};

__device__ __forceinline__ void qtrig_all(float q1, float q2, QTrig& t) {
    float sdq, cdq, c1v, c2v;
    gl_sincos(q1 - q2, sdq, cdq);
    c1v = gl_cosf(q1);
    c2v = gl_cosf(q2);
    float q1p = q1 + EPS_F, q1m = q1 - EPS_F;
    float sa, ca, sb, cb;
    gl_sincos(q1p - q2, sa, ca);
    gl_sincos(q1m - q2, sb, cb);
    float c1p = gl_cosf(q1p);
    float c1m = gl_cosf(q1m);
    float q2p = q2 + EPS_F, q2m = q2 - EPS_F;
    float sc, cc, sd, cd;
    gl_sincos(q1 - q2p, sc, cc);
    gl_sincos(q1 - q2m, sd, cd);
    float c2p = gl_cosf(q2p);
    float c2m = gl_cosf(q2m);

    float w1 = 1.0f - c1v;       // shared (1-c1), (1-c2) exactly as the
    float w2 = 1.0f - c2v;       // reference's CSE produced them
    t.cdq  = cdq;
    t.den0 = 2.0f * __builtin_fmaf(sdq, sdq, 1.0f);
    t.vv0  = w1 + w2;

    t.c_q1 = (v2f){ca, cb};
    v2f s1 = (v2f){sa, sb};
    t.den_q1 = 2.0f * pk_fma(s1, s1, (v2f){1.0f, 1.0f});
    t.vv_q1  = ((v2f){1.0f, 1.0f} - (v2f){c1p, c1m}) + w2;  // (1-c1+/-)+(1-c2)

    t.c_q2 = (v2f){cc, cd};
    v2f s2 = (v2f){sc, sd};
    t.den_q2 = 2.0f * pk_fma(s2, s2, (v2f){1.0f, 1.0f});
    t.vv_q2  = w1 + ((v2f){1.0f, 1.0f} - (v2f){c2p, c2m});  // (1-c1)+(1-c2+/-)
}

// Per-pair Hamiltonian, packed. Per-lane arithmetic is exactly the original
// ham_eval: denom = 2*fma(s,s,1) [cached]; num = fma(-(2p1)p2, c, fma(p1,p1,
// 2(p2*p2))); H = fma(10, VV, num/denom). Division scalarizes to two exact
// IEEE f32 divides — identical bits to the scalar form.
__device__ __forceinline__ float fd_q(float AB, float tt, v2f c, v2f den, v2f vv) {
    v2f num = pk_fma((v2f){-tt, -tt}, c, (v2f){AB, AB});
    v2f T = num / den;
    v2f H = pk_fma((v2f){10.0f, 10.0f}, vv, T);
    return (H.x - H.y) / TWOEPS_F;
}

// p1+/-eps pair at base trig (p2 fixed).
__device__ __forceinline__ float fd_p1(const QTrig& t, float p1, float p2) {
    v2f p1v = (v2f){p1, p1} + (v2f){EPS_F, -EPS_F};
    float B = 2.0f * (p2 * p2);
    v2f AB = pk_fma(p1v, p1v, (v2f){B, B});
    v2f tp = (2.0f * p1v) * p2;              // (2*p1') then *p2 — ref order
    v2f num = pk_fma(-tp, (v2f){t.cdq, t.cdq}, AB);
    v2f T = num / (v2f){t.den0, t.den0};
    v2f H = pk_fma((v2f){10.0f, 10.0f}, (v2f){t.vv0, t.vv0}, T);
    return (H.x - H.y) / TWOEPS_F;
}

// p2+/-eps pair at base trig (p1 fixed).
__device__ __forceinline__ float fd_p2(const QTrig& t, float p1, float p2) {
    v2f p2v = (v2f){p2, p2} + (v2f){EPS_F, -EPS_F};
    v2f B = 2.0f * (p2v * p2v);
    v2f AB = pk_fma((v2f){p1, p1}, (v2f){p1, p1}, B);
    v2f tp = (2.0f * p1) * p2v;              // (2*p1) scalar, then *p2'
    v2f num = pk_fma(-tp, (v2f){t.cdq, t.cdq}, AB);
    v2f T = num / (v2f){t.den0, t.den0};
    v2f H = pk_fma((v2f){10.0f, 10.0f}, (v2f){t.vv0, t.vv0}, T);
    return (H.x - H.y) / TWOEPS_F;
}

// Full 4-dim FD gradient from cached trig (identical arithmetic to before,
// +/- pairs packed into v_pk lanes).
__device__ __forceinline__ void grads_full(const QTrig& t, float p1, float p2,
                                           float& dHq1, float& dHq2,
                                           float& dHp1, float& dHp2) {
    float B  = 2.0f * (p2 * p2);
    float AB = __builtin_fmaf(p1, p1, B);
    float tt = (2.0f * p1) * p2;
    dHq1 = fd_q(AB, tt, t.c_q1, t.den_q1, t.vv_q1);
    dHq2 = fd_q(AB, tt, t.c_q2, t.den_q2, t.vv_q2);
    dHp1 = fd_p1(t, p1, p2);
    dHp2 = fd_p2(t, p1, p2);
}

// p-only gradient (midpoint call: reference's dH_dq lanes are dead code there).
__device__ __forceinline__ void grads_p(const QTrig& t, float p1, float p2,
                                        float& dHp1, float& dHp2) {
    dHp1 = fd_p1(t, p1, p2);
    dHp2 = fd_p2(t, p1, p2);
}

__global__ __launch_bounds__(256)
void mpc_rollout_kernel(const float* __restrict__ q0,
                        const float* __restrict__ p0,
                        const float* __restrict__ actions,
                        const float* __restrict__ target,
                        float* __restrict__ out,
                        int n, int T) {
    int i = blockIdx.x * blockDim.x + threadIdx.x;
    if (i >= n) return;

    float q1 = q0[2 * i],  q2 = q0[2 * i + 1];
    float p1 = p0[2 * i],  p2 = p0[2 * i + 1];
    float tg1 = target[0], tg2 = target[1];
    const float* act = actions + (size_t)i * (size_t)T;

    // XLA reduce: strict sequential accumulation in time order
    float running = 0.0f;

    QTrig qt;
    qtrig_all(q1, q2, qt);          // trig for the initial q

#pragma unroll 1
    for (int ts = 0; ts < T; ++ts) {
        float a = act[ts];

        // running cost at the PRE-step state (trajectory index ts), contracted
        {
            float e1 = angnorm(q1 - tg1);
            float e2 = angnorm(q2 - tg2);
            float pos = __builtin_fmaf(e1, e1, e2 * e2);
            float vel = __builtin_fmaf(p1, p1, p2 * p2);
            float c = __builtin_fmaf(0.01f, a * a, pos + vel);
            running += c;
        }

        // --- symplectic step, XLA-contracted (identical bits) ---
        float dq1g, dq2g, dp1g, dp2g;
        grads_full(qt, p1, p2, dq1g, dq2g, dp1g, dp2g);   // trig cached

        v2f pv  = (v2f){p1, p2};
        v2f dqg = (v2f){dq1g, dq2g};
        v2f dpg = (v2f){dp1g, dp2g};
        v2f ph  = pk_fma((v2f){-0.001f, -0.001f}, dpg,
                         pk_fma((v2f){-0.01f, -0.01f}, dqg, pv));

        float dpm1, dpm2;
        grads_p(qt, ph.x, ph.y, dpm1, dpm2);  // q unchanged -> same cached trig

        v2f qv = (v2f){q1, q2};
        v2f qn = pk_fma((v2f){0.02f, 0.02f}, (v2f){dpm1, dpm2}, qv);

        qtrig_all(qn.x, qn.y, qt);            // the ONLY trig work this step
        float dq1e, dq2e, dp1e, dp2e;
        grads_full(qt, ph.x, ph.y, dq1e, dq2e, dp1e, dp2e);

        v2f pn = pk_fma((v2f){-0.001f, -0.001f}, (v2f){dp1e, dp2e},
                        pk_fma((v2f){-0.01f, -0.01f}, (v2f){dq1e, dq2e}, ph));
        float pn2 = __builtin_fmaf(a, 0.02f, pn.y);   // torque on p[1]

        q1 = qn.x; q2 = qn.y; p1 = pn.x; p2 = pn2;
        // qt now holds trig for the new q -> reused at the next iteration
    }

    // terminal cost at trajectory index T, contracted
    float e1 = angnorm(q1 - tg1);
    float e2 = angnorm(q2 - tg2);
    float S  = __builtin_fmaf(e2, e2, e1 * e1);
    float S2 = __builtin_fmaf(p2, p2, p1 * p1);
    float term = __builtin_fmaf(10.0f, S, S2);

    out[i] = running + term;
}

extern "C" void kernel_launch(void* const* d_in, const int* in_sizes, int n_in,
                              void* d_out, int out_size, void* d_ws, size_t ws_size,
                              hipStream_t stream) {
    const float* q0      = (const float*)d_in[0];
    const float* p0      = (const float*)d_in[1];
    const float* actions = (const float*)d_in[2];
    const float* target  = (const float*)d_in[3];
    float* out = (float*)d_out;

    int n = in_sizes[0] / 2;        // q0 is (n, 2)
    int T = in_sizes[2] / n;        // actions is (n, T)

    int block = 256;
    int grid = (n + block - 1) / block;
    mpc_rollout_kernel<<<grid, block, 0, stream>>>(q0, p0, actions, target, out, n, T);
}

// Round 2
// 673.424 us; speedup vs baseline: 1.0425x; 1.0176x over previous
//
#include <hip/hip_runtime.h>
#include <cmath>

// All implicit ops single-rounded; FMA only where written explicitly
// (replicating XLA:CPU's FPOpFusion::Fast contraction). Output must stay
// BIT-IDENTICAL to prior rounds (passed, absmax 16.0).
#pragma clang fp contract(off)

#define PI_F     3.141592653589793f
#define TWOPI_F  6.283185307179586f
#define EPS_F    1e-5f
#define TWOEPS_F 2e-5f   // == f32(2e-5) exactly

// Packed 2xf32 — maps to v_pk_{add,mul,fma}_f32 on gfx950. Per-lane IEEE
// semantics identical to the scalar ops, so results are bit-identical;
// packing only halves the VALU issue count on paired computations.
typedef float v2f __attribute__((ext_vector_type(2)));

__device__ __forceinline__ v2f pk_fma(v2f a, v2f b, v2f c) {
    return __builtin_elementwise_fma(a, b, c);
}

// ---------------------------------------------------------------------------
// Branchless fused replica of glibc (>=2.28) scalar sinf/cosf (see prior
// session notes for the bit-exactness argument). Parity/sign selects applied
// AFTER the f64->f32 rounding — IEEE rounding commutes with sign flip.
// Valid for |y| < 120 (reduce_fast range); rollout angles stay |q| < ~30.
// ---------------------------------------------------------------------------
__device__ __forceinline__ void gl_sincos(float y, float& sout, float& cout) {
    const double hpi_inv = 0x1.45F306DC9C883p+23;  // 2/pi * 2^24
    const double hpi     = 0x1.921FB54442D18p+0;   // pi/2
    const double ps1 = -0x1.555545995a603p-3;
    const double ps2 =  0x1.1107605230bc4p-7;
    const double ps3 = -0x1.994eb3774cf24p-13;
    const double pc1 = -0x1.ffffffd0c621cp-2;
    const double pc2 =  0x1.55553e1068f19p-5;
    const double pc3 = -0x1.6c087e89a359dp-10;
    const double pc4 =  0x1.99343027bf8c3p-16;

    double x = (double)y;
    double r = x * hpi_inv;
    int n = ((int)r + 0x800000) >> 24;     // trunc + biased round, glibc exact
    double xr = x - (double)n * hpi;       // separate mul + sub (no fma)
    double x2 = xr * xr;

    // sine poly at xr, glibc grouping
    double x3 = xr * x2;
    double s1 = ps2 + x2 * ps3;
    double x7 = x3 * x2;
    double ss = xr + x3 * ps1;
    double psin = ss + x7 * s1;

    // cosine poly at x2, positive table, glibc grouping
    double x4 = x2 * x2;
    double c2 = pc3 + x2 * pc4;
    double c1 = 1.0 + x2 * pc1;
    double x6 = x4 * x2;
    double cc = c1 + x4 * pc2;
    double pcos = cc + x6 * c2;

    // round once, then exact sign/parity selects in f32
    float psin_f = (float)psin;
    float pcos_f = (float)pcos;
    float s_sel = (n & 1) ? pcos_f : psin_f;
    float c_sel = (n & 1) ? psin_f : pcos_f;
    sout = (n & 2) ? -s_sel : s_sel;
    cout = ((n + 1) & 2) ? -c_sel : c_sel;
}

__device__ __forceinline__ float gl_cosf(float y) {
    float s, c;
    gl_sincos(y, s, c);
    return c;
}

// ---------------------------------------------------------------------------
// angnorm with an exact bounded-range fmod, replacing the OCML fmodf libcall.
// fmod(t, c) is the EXACT remainder (always representable, never rounded),
// so any correct implementation is bit-identical to fmodf. Correctness for
// |t| < 64, c = f32(2pi): see prior round's derivation (k via one f64 mul is
// exact except at exact multiples of c, where the +/-c fixups are exact; the
// only discrepancy is +0 vs -0, absorbed by the following r - pi).
// ---------------------------------------------------------------------------
__device__ __forceinline__ float angnorm(float x) {
    const double inv_twopi = 1.0 / (double)TWOPI_F;  // RN64(1/f32(2pi))
    float t = x + PI_F;
    int k = (int)((double)t * inv_twopi);            // trunc toward zero
    float r = __builtin_fmaf((float)(-k), TWOPI_F, t);
    if (r >= TWOPI_F)  r -= TWOPI_F;   // k one too small at exact multiple
    if (r <= -TWOPI_F) r += TWOPI_F;   // k one too large at exact multiple
    if (r < 0.0f) r += TWOPI_F;        // reference's sign fixup (jnp.mod)
    return r - PI_F;
}

// ---------------------------------------------------------------------------
// Cross-step trig cache, FLATTENED into 15 independent locals (round 1's
// mixed scalar/v2f struct defeated SROA; AMDGPUPromoteAlloca then pushed it
// to LDS -> 4096 B/block + 8.2M bank-conflict cycles). Individual reference
// parameters each bind a standalone alloca that mem2reg deletes outright.
// Pair convention: .x = +eps variant, .y = -eps variant.
//   cdq,den0,vv0 : base cos(dq), 2*fma(s,s,1), (1-c1)+(1-c2)
//   c_q1,den_q1,vv_q1 : q1+/-eps variants; c_q2,den_q2,vv_q2 : q2+/-eps.
// ---------------------------------------------------------------------------
__device__ __forceinline__ void qtrig_all(float q1, float q2,
                                          float& cdq, float& den0, float& vv0,
                                          v2f& c_q1, v2f& den_q1, v2f& vv_q1,
                                          v2f& c_q2, v2f& den_q2, v2f& vv_q2) {
    float sdq, cdqv, c1v, c2v;
    gl_sincos(q1 - q2, sdq, cdqv);
    c1v = gl_cosf(q1);
    c2v = gl_cosf(q2);
    float q1p = q1 + EPS_F, q1m = q1 - EPS_F;
    float sa, ca, sb, cb;
    gl_sincos(q1p - q2, sa, ca);
    gl_sincos(q1m - q2, sb, cb);
    float c1p = gl_cosf(q1p);
    float c1m = gl_cosf(q1m);
    float q2p = q2 + EPS_F, q2m = q2 - EPS_F;
    float sc, cc, sd, cd;
    gl_sincos(q1 - q2p, sc, cc);
    gl_sincos(q1 - q2m, sd, cd);
    float c2p = gl_cosf(q2p);
    float c2m = gl_cosf(q2m);

    float w1 = 1.0f - c1v;       // shared (1-c1), (1-c2) exactly as the
    float w2 = 1.0f - c2v;       // reference's CSE produced them
    cdq  = cdqv;
    den0 = 2.0f * __builtin_fmaf(sdq, sdq, 1.0f);
    vv0  = w1 + w2;

    c_q1 = (v2f){ca, cb};
    v2f s1 = (v2f){sa, sb};
    den_q1 = 2.0f * pk_fma(s1, s1, (v2f){1.0f, 1.0f});
    vv_q1  = ((v2f){1.0f, 1.0f} - (v2f){c1p, c1m}) + w2;  // (1-c1+/-)+(1-c2)

    c_q2 = (v2f){cc, cd};
    v2f s2 = (v2f){sc, sd};
    den_q2 = 2.0f * pk_fma(s2, s2, (v2f){1.0f, 1.0f});
    vv_q2  = w1 + ((v2f){1.0f, 1.0f} - (v2f){c2p, c2m});  // (1-c1)+(1-c2+/-)
}

// Per-pair Hamiltonian, packed. Per-lane arithmetic is exactly the original
// ham_eval: denom = 2*fma(s,s,1) [cached]; num = fma(-(2p1)p2, c, fma(p1,p1,
// 2(p2*p2))); H = fma(10, VV, num/denom). Division scalarizes to two exact
// IEEE f32 divides — identical bits to the scalar form.
__device__ __forceinline__ float fd_q(float AB, float tt, v2f c, v2f den, v2f vv) {
    v2f num = pk_fma((v2f){-tt, -tt}, c, (v2f){AB, AB});
    v2f T = num / den;
    v2f H = pk_fma((v2f){10.0f, 10.0f}, vv, T);
    return (H.x - H.y) / TWOEPS_F;
}

// p1+/-eps pair at base trig (p2 fixed).
__device__ __forceinline__ float fd_p1(float cdq, float den0, float vv0,
                                       float p1, float p2) {
    v2f p1v = (v2f){p1, p1} + (v2f){EPS_F, -EPS_F};
    float B = 2.0f * (p2 * p2);
    v2f AB = pk_fma(p1v, p1v, (v2f){B, B});
    v2f tp = (2.0f * p1v) * p2;              // (2*p1') then *p2 — ref order
    v2f num = pk_fma(-tp, (v2f){cdq, cdq}, AB);
    v2f T = num / (v2f){den0, den0};
    v2f H = pk_fma((v2f){10.0f, 10.0f}, (v2f){vv0, vv0}, T);
    return (H.x - H.y) / TWOEPS_F;
}

// p2+/-eps pair at base trig (p1 fixed).
__device__ __forceinline__ float fd_p2(float cdq, float den0, float vv0,
                                       float p1, float p2) {
    v2f p2v = (v2f){p2, p2} + (v2f){EPS_F, -EPS_F};
    v2f B = 2.0f * (p2v * p2v);
    v2f AB = pk_fma((v2f){p1, p1}, (v2f){p1, p1}, B);
    v2f tp = (2.0f * p1) * p2v;              // (2*p1) scalar, then *p2'
    v2f num = pk_fma(-tp, (v2f){cdq, cdq}, AB);
    v2f T = num / (v2f){den0, den0};
    v2f H = pk_fma((v2f){10.0f, 10.0f}, (v2f){vv0, vv0}, T);
    return (H.x - H.y) / TWOEPS_F;
}

__global__ __launch_bounds__(256)
void mpc_rollout_kernel(const float* __restrict__ q0,
                        const float* __restrict__ p0,
                        const float* __restrict__ actions,
                        const float* __restrict__ target,
                        float* __restrict__ out,
                        int n, int T) {
    int i = blockIdx.x * blockDim.x + threadIdx.x;
    if (i >= n) return;

    float q1 = q0[2 * i],  q2 = q0[2 * i + 1];
    float p1 = p0[2 * i],  p2 = p0[2 * i + 1];
    float tg1 = target[0], tg2 = target[1];
    const float* act = actions + (size_t)i * (size_t)T;

    // XLA reduce: strict sequential accumulation in time order
    float running = 0.0f;

    // Flattened trig cache (see qtrig_all comment)
    float t_cdq, t_den0, t_vv0;
    v2f t_c_q1, t_den_q1, t_vv_q1;
    v2f t_c_q2, t_den_q2, t_vv_q2;
    qtrig_all(q1, q2, t_cdq, t_den0, t_vv0,
              t_c_q1, t_den_q1, t_vv_q1, t_c_q2, t_den_q2, t_vv_q2);

#pragma unroll 1
    for (int ts = 0; ts < T; ++ts) {
        float a = act[ts];

        // running cost at the PRE-step state (trajectory index ts), contracted
        {
            float e1 = angnorm(q1 - tg1);
            float e2 = angnorm(q2 - tg2);
            float pos = __builtin_fmaf(e1, e1, e2 * e2);
            float vel = __builtin_fmaf(p1, p1, p2 * p2);
            float c = __builtin_fmaf(0.01f, a * a, pos + vel);
            running += c;
        }

        // --- symplectic step, XLA-contracted (identical bits) ---
        // grads_full at (p1,p2) from cached trig
        float B0  = 2.0f * (p2 * p2);
        float AB0 = __builtin_fmaf(p1, p1, B0);
        float tt0 = (2.0f * p1) * p2;
        float dq1g = fd_q(AB0, tt0, t_c_q1, t_den_q1, t_vv_q1);
        float dq2g = fd_q(AB0, tt0, t_c_q2, t_den_q2, t_vv_q2);
        float dp1g = fd_p1(t_cdq, t_den0, t_vv0, p1, p2);
        float dp2g = fd_p2(t_cdq, t_den0, t_vv0, p1, p2);

        v2f pv  = (v2f){p1, p2};
        v2f dqg = (v2f){dq1g, dq2g};
        v2f dpg = (v2f){dp1g, dp2g};
        v2f ph  = pk_fma((v2f){-0.001f, -0.001f}, dpg,
                         pk_fma((v2f){-0.01f, -0.01f}, dqg, pv));

        // midpoint: p-only gradient (reference's dH_dq lanes are dead there)
        float dpm1 = fd_p1(t_cdq, t_den0, t_vv0, ph.x, ph.y);
        float dpm2 = fd_p2(t_cdq, t_den0, t_vv0, ph.x, ph.y);

        v2f qv = (v2f){q1, q2};
        v2f qn = pk_fma((v2f){0.02f, 0.02f}, (v2f){dpm1, dpm2}, qv);

        // the ONLY trig work this step
        qtrig_all(qn.x, qn.y, t_cdq, t_den0, t_vv0,
                  t_c_q1, t_den_q1, t_vv_q1, t_c_q2, t_den_q2, t_vv_q2);

        // grads_full at (ph1,ph2) with the new-q trig
        float B1  = 2.0f * (ph.y * ph.y);
        float AB1 = __builtin_fmaf(ph.x, ph.x, B1);
        float tt1 = (2.0f * ph.x) * ph.y;
        float dq1e = fd_q(AB1, tt1, t_c_q1, t_den_q1, t_vv_q1);
        float dq2e = fd_q(AB1, tt1, t_c_q2, t_den_q2, t_vv_q2);
        float dp1e = fd_p1(t_cdq, t_den0, t_vv0, ph.x, ph.y);
        float dp2e = fd_p2(t_cdq, t_den0, t_vv0, ph.x, ph.y);

        v2f pn = pk_fma((v2f){-0.001f, -0.001f}, (v2f){dp1e, dp2e},
                        pk_fma((v2f){-0.01f, -0.01f}, (v2f){dq1e, dq2e}, ph));
        float pn2 = __builtin_fmaf(a, 0.02f, pn.y);   // torque on p[1]

        q1 = qn.x; q2 = qn.y; p1 = pn.x; p2 = pn2;
        // trig cache now holds the new q -> reused at the next iteration
    }

    // terminal cost at trajectory index T, contracted
    float e1 = angnorm(q1 - tg1);
    float e2 = angnorm(q2 - tg2);
    float S  = __builtin_fmaf(e2, e2, e1 * e1);
    float S2 = __builtin_fmaf(p2, p2, p1 * p1);
    float term = __builtin_fmaf(10.0f, S, S2);

    out[i] = running + term;
}

extern "C" void kernel_launch(void* const* d_in, const int* in_sizes, int n_in,
                              void* d_out, int out_size, void* d_ws, size_t ws_size,
                              hipStream_t stream) {
    const float* q0      = (const float*)d_in[0];
    const float* p0      = (const float*)d_in[1];
    const float* actions = (const float*)d_in[2];
    const float* target  = (const float*)d_in[3];
    float* out = (float*)d_out;

    int n = in_sizes[0] / 2;        // q0 is (n, 2)
    int T = in_sizes[2] / n;        // actions is (n, T)

    int block = 256;
    int grid = (n + block - 1) / block;
    mpc_rollout_kernel<<<grid, block, 0, stream>>>(q0, p0, actions, target, out, n, T);
}